// Round 1
// baseline (1823.118 us; speedup 1.0000x reference)
//
#include <hip/hip_runtime.h>
#include <cstdio>
#include <cstdint>

// ---------------- problem constants ----------------
#define T_TOK 16384
#define H_DIM 2048
#define E_NUM 16
#define I_DIM 1408
#define TWO_I 2816
#define PMAX  34816     // 2*T + E*128: upper bound on padded slot count
#define MAXMT 272       // upper bound on m-tiles: 2*T/128 + E

typedef unsigned short ushort_t;
typedef __attribute__((ext_vector_type(8))) short bf16x8;          // 8 bf16 = 4 VGPRs (guide §3)
typedef __attribute__((ext_vector_type(4))) float f32x4;
typedef __attribute__((ext_vector_type(8))) unsigned short us8;

__device__ __forceinline__ ushort_t f2bf(float x) {
  union { float f; unsigned int u; } v; v.f = x;
  unsigned int r = v.u + 0x7fffu + ((v.u >> 16) & 1u);   // RNE
  return (ushort_t)(r >> 16);
}

__device__ __forceinline__ void async_copy16(const void* g, void* l) {
  __builtin_amdgcn_global_load_lds(
      (const __attribute__((address_space(1))) unsigned int*)g,
      (__attribute__((address_space(3))) unsigned int*)l, 16, 0, 0);
}

// ---------------- routing ----------------
__global__ void zero_small(int* counts, int* fill, int* ntl) {
  int i = threadIdx.x;
  if (i < E_NUM) { counts[i] = 0; fill[i] = 0; }
  if (i == 0) ntl[0] = 0;
}

__global__ void router_kernel(const float* __restrict__ logits,
                              int* __restrict__ tok_e, float* __restrict__ tok_w,
                              int* __restrict__ counts) {
  int t = blockIdx.x * 256 + threadIdx.x;
  if (t >= T_TOK) return;
  const float* lp = logits + (size_t)t * E_NUM;
  float b1 = -1e30f, b2 = -1e30f; int i1 = 0, i2 = 0;
#pragma unroll
  for (int e = 0; e < E_NUM; ++e) {
    float v = lp[e];
    if (v > b1) { b2 = b1; i2 = i1; b1 = v; i1 = e; }
    else if (v > b2) { b2 = v; i2 = e; }
  }
  // renormalized top-2 softmax: full denominator cancels
  float w1 = 1.f / (1.f + __expf(b2 - b1));
  tok_e[2 * t] = i1; tok_e[2 * t + 1] = i2;
  tok_w[2 * t] = w1; tok_w[2 * t + 1] = 1.f - w1;
  atomicAdd(&counts[i1], 1);
  atomicAdd(&counts[i2], 1);
}

__global__ void scan_kernel(const int* __restrict__ counts, int* __restrict__ base_e,
                            int* __restrict__ tile_expert, int* __restrict__ tile_base,
                            int* __restrict__ ntl) {
  if (threadIdx.x != 0) return;
  int base = 0, nt = 0;
  for (int e = 0; e < E_NUM; ++e) {
    base_e[e] = base;
    int c = counts[e];
    int tiles = (c + 127) >> 7;
    for (int ti = 0; ti < tiles; ++ti) { tile_expert[nt] = e; tile_base[nt] = base + ti * 128; ++nt; }
    base += tiles << 7;
  }
  ntl[0] = nt;
}

__global__ void slot_init_kernel(int* st, float* sw) {
  int i = blockIdx.x * 256 + threadIdx.x;
  if (i < PMAX) { st[i] = 0; sw[i] = 0.f; }   // pad slots: token 0, weight 0
}

__global__ void scatter_kernel(const int* __restrict__ tok_e, const float* __restrict__ tok_w,
                               const int* __restrict__ base_e, int* __restrict__ fill,
                               int* __restrict__ st, float* __restrict__ sw) {
  int t = blockIdx.x * 256 + threadIdx.x;
  if (t >= T_TOK) return;
#pragma unroll
  for (int k = 0; k < 2; ++k) {
    int e = tok_e[2 * t + k];
    int pos = atomicAdd(&fill[e], 1);
    int slot = base_e[e] + pos;
    st[slot] = t; sw[slot] = tok_w[2 * t + k];
  }
}

// ---------------- fp32 -> bf16 conversion ----------------
__device__ __forceinline__ us8 pack8(float4 a, float4 b) {
  us8 r;
  r[0] = f2bf(a.x); r[1] = f2bf(a.y); r[2] = f2bf(a.z); r[3] = f2bf(a.w);
  r[4] = f2bf(b.x); r[5] = f2bf(b.y); r[6] = f2bf(b.z); r[7] = f2bf(b.w);
  return r;
}

__global__ void cvt_hidden(const float* __restrict__ src, ushort_t* __restrict__ dst) {
  size_t i8 = ((size_t)blockIdx.x * 256 + threadIdx.x) * 8;
  const float4* s = (const float4*)(src + i8);
  *(us8*)(dst + i8) = pack8(s[0], s[1]);
}

// permute w13 rows: gate row n (<I) -> (n/16)*32 + n%16 ; up row n (>=I) -> ((n-I)/16)*32 + 16 + (n-I)%16
__global__ void cvt_w13(const float* __restrict__ src, ushort_t* __restrict__ dst) {
  size_t i8 = ((size_t)blockIdx.x * 256 + threadIdx.x) * 8;
  const size_t per_e = (size_t)TWO_I * H_DIM;
  int e = (int)(i8 / per_e);
  size_t rem = i8 - (size_t)e * per_e;
  int n = (int)(rem / H_DIM);
  int c = (int)(rem - (size_t)n * H_DIM);
  int np;
  if (n < I_DIM) np = ((n >> 4) << 5) + (n & 15);
  else { int m = n - I_DIM; np = ((m >> 4) << 5) + 16 + (m & 15); }
  const float4* s = (const float4*)(src + i8);
  *(us8*)(dst + (size_t)e * per_e + (size_t)np * H_DIM + c) = pack8(s[0], s[1]);
}

__global__ void cvt_w2(const float* __restrict__ src, ushort_t* __restrict__ dst) {
  size_t i8 = ((size_t)blockIdx.x * 256 + threadIdx.x) * 8;
  const float4* s = (const float4*)(src + i8);
  *(us8*)(dst + i8) = pack8(s[0], s[1]);
}

// ---------------- GEMM1: act = silu(X @ W1^T) * (X @ W3^T), token-gathered A ----------------
// LDS swizzle: 16B cell for (row m, k-chunk kc) lives at unit m*8 + (kc ^ (m&7)).
// Conflict-free ds_read_b128 frag reads AND lane-contiguous global_load_lds staging.
__global__ __launch_bounds__(256, 2) void gemm1_kernel(
    const ushort_t* __restrict__ Xb, const ushort_t* __restrict__ W13p,
    ushort_t* __restrict__ Act, const int* __restrict__ slot_token,
    const int* __restrict__ tile_expert, const int* __restrict__ tile_base,
    const int* __restrict__ ntl) {
  const int mt = blockIdx.y;
  if (mt >= ntl[0]) return;
  const int e = tile_expert[mt];
  const int slot0 = tile_base[mt];
  const int n0 = blockIdx.x * 128;

  __shared__ ushort_t As[128 * 64];
  __shared__ ushort_t Bs[128 * 64];
  __shared__ int toks[128];

  const int tid = threadIdx.x;
  if (tid < 128) toks[tid] = slot_token[slot0 + tid];
  __syncthreads();

  const int wave = tid >> 6;
  const int lane = tid & 63;
  const int r = lane & 15;
  const int q = lane >> 4;
  const int wm = wave >> 1;
  const int wn = wave & 1;

  const ushort_t* a_src[4];
  const ushort_t* b_src[4];
  ushort_t* a_dst[4];
  ushort_t* b_dst[4];
#pragma unroll
  for (int s = 0; s < 4; ++s) {
    int u = wave * 256 + s * 64 + lane;
    int m = u >> 3;
    int kc = (u & 7) ^ (m & 7);
    a_src[s] = Xb + (size_t)toks[m] * H_DIM + kc * 8;
    b_src[s] = W13p + (size_t)e * ((size_t)TWO_I * H_DIM) + (size_t)(n0 + m) * H_DIM + kc * 8;
    a_dst[s] = &As[(size_t)u * 8];
    b_dst[s] = &Bs[(size_t)u * 8];
  }

  int aoff[2][4], boff[2][4];
#pragma unroll
  for (int kh = 0; kh < 2; ++kh)
#pragma unroll
    for (int i = 0; i < 4; ++i) {
      int m = wm * 64 + i * 16 + r;
      aoff[kh][i] = (m * 8 + ((kh * 4 + q) ^ (r & 7))) * 8;
      int n = wn * 64 + i * 16 + r;
      boff[kh][i] = (n * 8 + ((kh * 4 + q) ^ (r & 7))) * 8;
    }

  f32x4 acc[4][4];
#pragma unroll
  for (int i = 0; i < 4; ++i)
#pragma unroll
    for (int j = 0; j < 4; ++j) acc[i][j] = (f32x4)(0.f);

  for (int kt = 0; kt < H_DIM / 64; ++kt) {
    const int koff = kt * 64;
#pragma unroll
    for (int s = 0; s < 4; ++s) {
      async_copy16(a_src[s] + koff, a_dst[s]);
      async_copy16(b_src[s] + koff, b_dst[s]);
    }
    __syncthreads();
#pragma unroll
    for (int kh = 0; kh < 2; ++kh) {
      bf16x8 af[4], bfr[4];
#pragma unroll
      for (int i = 0; i < 4; ++i) af[i] = *(const bf16x8*)&As[aoff[kh][i]];
#pragma unroll
      for (int j = 0; j < 4; ++j) bfr[j] = *(const bf16x8*)&Bs[boff[kh][j]];
#pragma unroll
      for (int i = 0; i < 4; ++i)
#pragma unroll
        for (int j = 0; j < 4; ++j)
          acc[i][j] = __builtin_amdgcn_mfma_f32_16x16x32_bf16(af[i], bfr[j], acc[i][j], 0, 0, 0);
    }
    __syncthreads();
  }

  // epilogue: frag pair (2jj, 2jj+1) = (gate, up) for act column group g
#pragma unroll
  for (int i = 0; i < 4; ++i) {
    const int row = slot0 + wm * 64 + i * 16 + q * 4;
#pragma unroll
    for (int jj = 0; jj < 2; ++jj) {
      const int g = 4 * (int)blockIdx.x + 2 * wn + jj;
      const int col = g * 16 + r;
      const f32x4 gv = acc[i][2 * jj];
      const f32x4 uv = acc[i][2 * jj + 1];
#pragma unroll
      for (int reg = 0; reg < 4; ++reg) {
        float gate = gv[reg];
        float a = gate / (1.f + __expf(-gate)) * uv[reg];
        Act[(size_t)(row + reg) * I_DIM + col] = f2bf(a);
      }
    }
  }
}

// ---------------- GEMM2: out[token] += w * (act @ W2^T) ----------------
__global__ __launch_bounds__(256, 2) void gemm2_kernel(
    const ushort_t* __restrict__ Act, const ushort_t* __restrict__ W2b,
    float* __restrict__ Out, const int* __restrict__ slot_token,
    const float* __restrict__ slot_w, const int* __restrict__ tile_expert,
    const int* __restrict__ tile_base, const int* __restrict__ ntl) {
  const int mt = blockIdx.y;
  if (mt >= ntl[0]) return;
  const int e = tile_expert[mt];
  const int slot0 = tile_base[mt];
  const int n0 = blockIdx.x * 128;

  __shared__ ushort_t As[128 * 64];
  __shared__ ushort_t Bs[128 * 64];
  __shared__ int toks[128];
  __shared__ float wgt[128];

  const int tid = threadIdx.x;
  if (tid < 128) { toks[tid] = slot_token[slot0 + tid]; wgt[tid] = slot_w[slot0 + tid]; }

  const int wave = tid >> 6;
  const int lane = tid & 63;
  const int r = lane & 15;
  const int q = lane >> 4;
  const int wm = wave >> 1;
  const int wn = wave & 1;

  const ushort_t* a_src[4];
  const ushort_t* b_src[4];
  ushort_t* a_dst[4];
  ushort_t* b_dst[4];
#pragma unroll
  for (int s = 0; s < 4; ++s) {
    int u = wave * 256 + s * 64 + lane;
    int m = u >> 3;
    int kc = (u & 7) ^ (m & 7);
    a_src[s] = Act + (size_t)(slot0 + m) * I_DIM + kc * 8;
    b_src[s] = W2b + (size_t)e * ((size_t)H_DIM * I_DIM) + (size_t)(n0 + m) * I_DIM + kc * 8;
    a_dst[s] = &As[(size_t)u * 8];
    b_dst[s] = &Bs[(size_t)u * 8];
  }

  int aoff[2][4], boff[2][4];
#pragma unroll
  for (int kh = 0; kh < 2; ++kh)
#pragma unroll
    for (int i = 0; i < 4; ++i) {
      int m = wm * 64 + i * 16 + r;
      aoff[kh][i] = (m * 8 + ((kh * 4 + q) ^ (r & 7))) * 8;
      int n = wn * 64 + i * 16 + r;
      boff[kh][i] = (n * 8 + ((kh * 4 + q) ^ (r & 7))) * 8;
    }

  f32x4 acc[4][4];
#pragma unroll
  for (int i = 0; i < 4; ++i)
#pragma unroll
    for (int j = 0; j < 4; ++j) acc[i][j] = (f32x4)(0.f);

  for (int kt = 0; kt < I_DIM / 64; ++kt) {
    const int koff = kt * 64;
#pragma unroll
    for (int s = 0; s < 4; ++s) {
      async_copy16(a_src[s] + koff, a_dst[s]);
      async_copy16(b_src[s] + koff, b_dst[s]);
    }
    __syncthreads();
#pragma unroll
    for (int kh = 0; kh < 2; ++kh) {
      bf16x8 af[4], bfr[4];
#pragma unroll
      for (int i = 0; i < 4; ++i) af[i] = *(const bf16x8*)&As[aoff[kh][i]];
#pragma unroll
      for (int j = 0; j < 4; ++j) bfr[j] = *(const bf16x8*)&Bs[boff[kh][j]];
#pragma unroll
      for (int i = 0; i < 4; ++i)
#pragma unroll
        for (int j = 0; j < 4; ++j)
          acc[i][j] = __builtin_amdgcn_mfma_f32_16x16x32_bf16(af[i], bfr[j], acc[i][j], 0, 0, 0);
    }
    __syncthreads();
  }

#pragma unroll
  for (int i = 0; i < 4; ++i) {
#pragma unroll
    for (int j = 0; j < 4; ++j) {
      const int col = n0 + wn * 64 + j * 16 + r;
#pragma unroll
      for (int reg = 0; reg < 4; ++reg) {
        const int rl = wm * 64 + i * 16 + q * 4 + reg;
        const int tok = toks[rl];
        const float w = wgt[rl];
        atomicAdd(&Out[(size_t)tok * H_DIM + col], w * acc[i][j][reg]);
      }
    }
  }
}

// ---------------- launch ----------------
extern "C" void kernel_launch(void* const* d_in, const int* in_sizes, int n_in,
                              void* d_out, int out_size, void* d_ws, size_t ws_size,
                              hipStream_t stream) {
  const float* hidden = (const float*)d_in[0];
  const float* logits = (const float*)d_in[1];
  const float* w13    = (const float*)d_in[2];
  const float* w2     = (const float*)d_in[3];
  float* out = (float*)d_out;
  char* ws = (char*)d_ws;

  size_t off = 0;
  ushort_t* hid_b = (ushort_t*)(ws + off); off += (size_t)T_TOK * H_DIM * 2;          // 64 MiB
  ushort_t* w13p  = (ushort_t*)(ws + off); off += (size_t)E_NUM * TWO_I * H_DIM * 2;  // 176 MiB
  ushort_t* w2b   = (ushort_t*)ws;  // overlays hid_b+w13p; written only AFTER gemm1
  ushort_t* act   = (ushort_t*)(ws + off); off += (size_t)PMAX * I_DIM * 2;           // 93.5 MiB
  int*   stok  = (int*)(ws + off);  off += (size_t)PMAX * 4;
  float* swt   = (float*)(ws + off); off += (size_t)PMAX * 4;
  int*   tok_e = (int*)(ws + off);  off += (size_t)T_TOK * 2 * 4;
  float* tok_w = (float*)(ws + off); off += (size_t)T_TOK * 2 * 4;
  int* counts = (int*)(ws + off); off += 256;
  int* fill   = (int*)(ws + off); off += 256;
  int* base_e = (int*)(ws + off); off += 256;
  int* texp   = (int*)(ws + off); off += MAXMT * 4;
  int* tbase  = (int*)(ws + off); off += MAXMT * 4;
  int* ntl    = (int*)(ws + off); off += 256;

  if (off > ws_size) {
    fprintf(stderr, "FusedMoE: ws too small: need %zu have %zu\n", off, ws_size);
    return;
  }

  zero_small<<<1, 64, 0, stream>>>(counts, fill, ntl);
  router_kernel<<<T_TOK / 256, 256, 0, stream>>>(logits, tok_e, tok_w, counts);
  scan_kernel<<<1, 64, 0, stream>>>(counts, base_e, texp, tbase, ntl);
  slot_init_kernel<<<(PMAX + 255) / 256, 256, 0, stream>>>(stok, swt);
  scatter_kernel<<<T_TOK / 256, 256, 0, stream>>>(tok_e, tok_w, base_e, fill, stok, swt);

  cvt_hidden<<<(T_TOK * H_DIM / 8) / 256, 256, 0, stream>>>(hidden, hid_b);
  cvt_w13<<<(unsigned)((size_t)E_NUM * TWO_I * H_DIM / 8 / 256), 256, 0, stream>>>(w13, w13p);

  dim3 g1(TWO_I / 128, MAXMT);
  gemm1_kernel<<<g1, 256, 0, stream>>>(hid_b, w13p, act, stok, texp, tbase, ntl);

  cvt_w2<<<(unsigned)((size_t)E_NUM * H_DIM * I_DIM / 8 / 256), 256, 0, stream>>>(w2, w2b);
  hipMemsetAsync(d_out, 0, (size_t)T_TOK * H_DIM * 4, stream);

  dim3 g2(H_DIM / 128, MAXMT);
  gemm2_kernel<<<g2, 256, 0, stream>>>(act, w2b, out, stok, swt, texp, tbase, ntl);
}